// Round 4
// baseline (431.361 us; speedup 1.0000x reference)
//
#include <hip/hip_runtime.h>

constexpr int L = 128;

// Branch-free gather: the circular mask and all OOB handling are folded into
// weight/address selects so the compiler can batch ALL 16 loads (2 pixels x 8
// corners) per thread before any consumption. Masked lanes load vol[0]
// (broadcast line, ~free) with zero weight -> no extra fetch traffic.
// Tile 64(k) x 8(j); wave = 64 consecutive k in one row (compact footprint).
// __launch_bounds__(256,8) pins VGPR<=64 -> 8 waves/SIMD -> ~128 outstanding
// loads per SIMD to cover the L2/L3 miss latency.
__global__ __launch_bounds__(256, 8) void xfel_proj(
    const float* __restrict__ rotmat,   // [B,3,3]
    const float* __restrict__ vol,      // [L,L,L] as [D,H,W]
    float* __restrict__ out)            // [B,L,L]
{
    const int tid  = threadIdx.x;
    const int lane = tid & 63;
    const int wv   = tid >> 6;                   // 0..3
    const int t    = blockIdx.x;                 // 0..31: 2 k-tiles x 16 j-tiles
    const int b    = blockIdx.y;
    const int k    = ((t & 1) << 6) | lane;
    const int jb   = ((t >> 1) << 3) + wv;       // rows jb, jb+4

    // rotation is block-uniform -> scalar loads
    const float* __restrict__ R = rotmat + b * 9;
    const float R00 = R[0], R01 = R[1], R02 = R[2];
    const float R10 = R[3], R11 = R[4], R12 = R[5];
    const float R20 = R[6], R21 = R[7], R22 = R[8];

    const float lk = -1.0f + (float)k * (2.0f / 127.0f);
    const float yc = -1.0f + 64.0f * (2.0f / 127.0f);   // lin[64]
    const float cx = yc * R10 + lk * R20 + 1.0f;
    const float cy = yc * R11 + lk * R21 + 1.0f;
    const float cz = yc * R12 + lk * R22 + 1.0f;

    const float ak  = (float)(k - 64) * (128.0f / 127.0f);
    const float ak2 = ak * ak;
    const float thr = 57.6f * 57.6f;                    // (0.9*L/2)^2

    float wt[2][6];   // wx0,wx1,wy0,wy1,wz0,wz1 (vis folded into wz)
    float v[2][8];    // corner samples, (z,y,x) bit order

    #pragma unroll
    for (int m = 0; m < 2; ++m) {
        const int j = jb + (m << 2);
        const float aj = (float)(j - 64) * (128.0f / 127.0f);
        const bool vis = (aj * aj + ak2 < thr);

        const float lj = -1.0f + (float)j * (2.0f / 127.0f);
        const float gx = (lj * R00 + cx) * 63.5f;
        const float gy = (lj * R01 + cy) * 63.5f;
        const float gz = (lj * R02 + cz) * 63.5f;

        const float fx0 = floorf(gx), fy0 = floorf(gy), fz0 = floorf(gz);
        const int ix = (int)fx0, iy = (int)fy0, iz = (int)fz0;
        const float fx = gx - fx0, fy = gy - fy0, fz = gz - fz0;

        // two-sided validity folded into weights (zeros padding, no branches)
        wt[m][0] = ((unsigned)ix       < 128u) ? 1.0f - fx : 0.0f;
        wt[m][1] = ((unsigned)(ix + 1) < 128u) ? fx        : 0.0f;
        wt[m][2] = ((unsigned)iy       < 128u) ? 1.0f - fy : 0.0f;
        wt[m][3] = ((unsigned)(iy + 1) < 128u) ? fy        : 0.0f;
        wt[m][4] = (vis && (unsigned)iz       < 128u) ? 1.0f - fz : 0.0f;
        wt[m][5] = (vis && (unsigned)(iz + 1) < 128u) ? fz        : 0.0f;

        const int x0 = min(max(ix, 0), 127), x1 = min(max(ix + 1, 0), 127);
        const int y0 = min(max(iy, 0), 127), y1 = min(max(iy + 1, 0), 127);
        const int z0 = min(max(iz, 0), 127), z1 = min(max(iz + 1, 0), 127);

        // 4 plane/row bases + 2 x offsets; select to 0 for masked lanes so
        // their loads broadcast from line 0 instead of fetching real lines
        int b00 = (z0 << 14) | (y0 << 7);
        int b01 = (z0 << 14) | (y1 << 7);
        int b10 = (z1 << 14) | (y0 << 7);
        int b11 = (z1 << 14) | (y1 << 7);
        int xs0 = x0, xs1 = x1;
        if (!vis) { b00 = 0; b01 = 0; b10 = 0; b11 = 0; xs0 = 0; xs1 = 0; }

        v[m][0] = vol[b00 + xs0];
        v[m][1] = vol[b00 + xs1];
        v[m][2] = vol[b01 + xs0];
        v[m][3] = vol[b01 + xs1];
        v[m][4] = vol[b10 + xs0];
        v[m][5] = vol[b10 + xs1];
        v[m][6] = vol[b11 + xs0];
        v[m][7] = vol[b11 + xs1];
    }

    #pragma unroll
    for (int m = 0; m < 2; ++m) {
        const int j = jb + (m << 2);
        const float r0 = wt[m][2] * (wt[m][0] * v[m][0] + wt[m][1] * v[m][1])
                       + wt[m][3] * (wt[m][0] * v[m][2] + wt[m][1] * v[m][3]);
        const float r1 = wt[m][2] * (wt[m][0] * v[m][4] + wt[m][1] * v[m][5])
                       + wt[m][3] * (wt[m][0] * v[m][6] + wt[m][1] * v[m][7]);
        const float res = wt[m][4] * r0 + wt[m][5] * r1;
        __builtin_nontemporal_store(res, out + (b * L + j) * L + k);
    }
}

extern "C" void kernel_launch(void* const* d_in, const int* in_sizes, int n_in,
                              void* d_out, int out_size, void* d_ws, size_t ws_size,
                              hipStream_t stream) {
    const float* rotmat = (const float*)d_in[0];
    const float* vol    = (const float*)d_in[1];
    float* out          = (float*)d_out;
    const int B = in_sizes[0] / 9;               // 2048
    dim3 grid(32, B);                            // 2 k-tiles x 16 j-tiles
    xfel_proj<<<grid, dim3(256), 0, stream>>>(rotmat, vol, out);
}

// Round 5
// 254.453 us; speedup vs baseline: 1.6952x; 1.6952x over previous
//
#include <hip/hip_runtime.h>

constexpr int L = 128;

// 4-byte-aligned float2: lets one gather fetch both x-corners (same cache
// line ~15/16 of the time) -> halves L1 line transactions vs two dword loads.
typedef float f2v __attribute__((ext_vector_type(2), aligned(4)));

struct Px {
    int b00, b01, b10, b11, xe;
    float wa, wb, wy0, wy1, wz0, wz1;
    bool alive;
};

__device__ __forceinline__ Px setup_px(float lj, float cx, float cy, float cz,
                                       float R00, float R01, float R02, bool vis)
{
    Px p;
    // grid_sample align_corners=True voxel coords
    const float gx = (lj * R00 + cx) * 63.5f;
    const float gy = (lj * R01 + cy) * 63.5f;
    const float gz = (lj * R02 + cz) * 63.5f;
    const float fx0 = floorf(gx), fy0 = floorf(gy), fz0 = floorf(gz);
    const int ix = (int)fx0, iy = (int)fy0, iz = (int)fz0;
    const float fx = gx - fx0, fy = gy - fy0, fz = gz - fz0;

    // per-corner validity -> weights (zeros padding), branch-free
    const float wx0 = ((unsigned)ix       < 128u) ? 1.0f - fx : 0.0f;
    const float wx1 = ((unsigned)(ix + 1) < 128u) ? fx        : 0.0f;
    // map (wx0@x0, wx1@x1) onto the loaded pair (v[xe], v[xe+1]):
    //   ix in [0,126]: (wx0, wx1);  ix==-1: (wx1, 0);  ix==127: (0, wx0)
    p.wa = (ix == -1) ? wx1 : ((ix == 127) ? 0.0f : wx0);
    p.wb = (ix == 127) ? wx0 : ((ix == -1) ? 0.0f : wx1);
    p.wy0 = ((unsigned)iy       < 128u) ? 1.0f - fy : 0.0f;
    p.wy1 = ((unsigned)(iy + 1) < 128u) ? fy        : 0.0f;
    p.wz0 = (vis && (unsigned)iz       < 128u) ? 1.0f - fz : 0.0f;
    p.wz1 = (vis && (unsigned)(iz + 1) < 128u) ? fz        : 0.0f;

    p.alive = vis && (ix >= -1) && (ix <= 127) && (iy >= -1) && (iy <= 127)
                  && (iz >= -1) && (iz <= 127);

    int xe = min(max(ix, 0), 126);
    int y0 = min(max(iy, 0), 127), y1 = min(max(iy + 1, 0), 127);
    int z0 = min(max(iz, 0), 127), z1 = min(max(iz + 1, 0), 127);
    if (!p.alive) { xe = 0; y0 = 0; y1 = 0; z0 = 0; z1 = 0; }  // dead -> line 0
    p.xe  = xe;
    p.b00 = (z0 << 14) | (y0 << 7);
    p.b01 = (z0 << 14) | (y1 << 7);
    p.b10 = (z1 << 14) | (y0 << 7);
    p.b11 = (z1 << 14) | (y1 << 7);
    return p;
}

__device__ __forceinline__ float combine_px(const Px& p,
                                            f2v a00, f2v a01, f2v a10, f2v a11)
{
    const float r00 = p.wa * a00.x + p.wb * a00.y;
    const float r01 = p.wa * a01.x + p.wb * a01.y;
    const float r10 = p.wa * a10.x + p.wb * a10.y;
    const float r11 = p.wa * a11.x + p.wb * a11.y;
    return p.wz0 * (p.wy0 * r00 + p.wy1 * r01)
         + p.wz1 * (p.wy0 * r10 + p.wy1 * r11);
}

// Tile 64(k) x 8(j); block = 4 waves; wave w -> rows (jb+2w, jb+2w+1), lane -> k
// (wave = 64 consecutive k in one row: compact line footprint). Two wave-
// uniform ballot early-outs (mask, then fully-outside-volume). The 8 paired
// gathers per thread are fenced from their consumers by sched_barrier(0) so
// the compiler keeps them all in flight.
__global__ __launch_bounds__(256, 4) void xfel_proj(
    const float* __restrict__ rotmat,   // [B,3,3]
    const float* __restrict__ vol,      // [L,L,L] as [D,H,W]
    float* __restrict__ out)            // [B,L,L]
{
    const int tid  = threadIdx.x;
    const int lane = tid & 63;
    const int wv   = tid >> 6;                    // 0..3
    const int t    = blockIdx.x;                  // 2 khalf x 16 jtile
    const int b    = blockIdx.y;
    const int k    = ((t & 1) << 6) | lane;
    const int j0   = ((t >> 1) << 3) + (wv << 1); // rows j0, j0+1

    const int oidx0 = (b * L + j0) * L + k;
    const int oidx1 = oidx0 + L;

    // circular mask
    const float stepw = 128.0f / 127.0f;
    const float ak  = (float)(k - 64) * stepw;
    const float ak2 = ak * ak;
    const float thr = 57.6f * 57.6f;              // (0.9*L/2)^2
    const float aj0 = (float)(j0 - 64) * stepw;
    const float aj1 = (float)(j0 - 63) * stepw;
    const bool vis0 = (aj0 * aj0 + ak2 < thr);
    const bool vis1 = (aj1 * aj1 + ak2 < thr);

    if (__ballot((int)(vis0 || vis1)) == 0ull) {  // whole wave masked
        __builtin_nontemporal_store(0.0f, out + oidx0);
        __builtin_nontemporal_store(0.0f, out + oidx1);
        return;
    }

    // rotation is block-uniform -> scalar loads
    const float* __restrict__ R = rotmat + b * 9;
    const float R00 = R[0], R01 = R[1], R02 = R[2];
    const float R10 = R[3], R11 = R[4], R12 = R[5];
    const float R20 = R[6], R21 = R[7], R22 = R[8];

    const float lk = -1.0f + (float)k * (2.0f / 127.0f);
    const float yc = -1.0f + 64.0f * (2.0f / 127.0f);   // lin[64]
    const float cx = yc * R10 + lk * R20 + 1.0f;
    const float cy = yc * R11 + lk * R21 + 1.0f;
    const float cz = yc * R12 + lk * R22 + 1.0f;

    const float lj0 = -1.0f + (float)j0 * (2.0f / 127.0f);
    const float lj1 = lj0 + (2.0f / 127.0f);

    const Px p0 = setup_px(lj0, cx, cy, cz, R00, R01, R02, vis0);
    const Px p1 = setup_px(lj1, cx, cy, cz, R00, R01, R02, vis1);

    if (__ballot((int)(p0.alive || p1.alive)) == 0ull) {  // whole wave outside
        __builtin_nontemporal_store(0.0f, out + oidx0);
        __builtin_nontemporal_store(0.0f, out + oidx1);
        return;
    }

    // 8 paired gathers, batched; consumers fenced below
    const f2v A00 = *(const f2v*)(vol + p0.b00 + p0.xe);
    const f2v A01 = *(const f2v*)(vol + p0.b01 + p0.xe);
    const f2v A10 = *(const f2v*)(vol + p0.b10 + p0.xe);
    const f2v A11 = *(const f2v*)(vol + p0.b11 + p0.xe);
    const f2v B00 = *(const f2v*)(vol + p1.b00 + p1.xe);
    const f2v B01 = *(const f2v*)(vol + p1.b01 + p1.xe);
    const f2v B10 = *(const f2v*)(vol + p1.b10 + p1.xe);
    const f2v B11 = *(const f2v*)(vol + p1.b11 + p1.xe);

    __builtin_amdgcn_sched_barrier(0);   // keep all 8 loads in flight

    const float res0 = combine_px(p0, A00, A01, A10, A11);
    const float res1 = combine_px(p1, B00, B01, B10, B11);

    __builtin_nontemporal_store(res0, out + oidx0);
    __builtin_nontemporal_store(res1, out + oidx1);
}

extern "C" void kernel_launch(void* const* d_in, const int* in_sizes, int n_in,
                              void* d_out, int out_size, void* d_ws, size_t ws_size,
                              hipStream_t stream) {
    const float* rotmat = (const float*)d_in[0];
    const float* vol    = (const float*)d_in[1];
    float* out          = (float*)d_out;
    const int B = in_sizes[0] / 9;                // 2048
    dim3 grid(32, B);                             // 2 khalf x 16 jtile
    xfel_proj<<<grid, dim3(256), 0, stream>>>(rotmat, vol, out);
}

// Round 6
// 226.660 us; speedup vs baseline: 1.9031x; 1.1226x over previous
//
#include <hip/hip_runtime.h>

constexpr int L = 128;

typedef float f2v __attribute__((ext_vector_type(2), aligned(4)));

struct Px {
    int b00, b01, b10, b11, xe;
    float wa, wb, wy0, wy1, wz0, wz1;
    bool alive;
};

__device__ __forceinline__ Px setup_px(float lj, float cx, float cy, float cz,
                                       float R00, float R01, float R02, bool vis)
{
    Px p;
    // grid_sample align_corners=True voxel coords
    const float gx = (lj * R00 + cx) * 63.5f;
    const float gy = (lj * R01 + cy) * 63.5f;
    const float gz = (lj * R02 + cz) * 63.5f;
    const float fx0 = floorf(gx), fy0 = floorf(gy), fz0 = floorf(gz);
    const int ix = (int)fx0, iy = (int)fy0, iz = (int)fz0;
    const float fx = gx - fx0, fy = gy - fy0, fz = gz - fz0;

    const float wx0 = ((unsigned)ix       < 128u) ? 1.0f - fx : 0.0f;
    const float wx1 = ((unsigned)(ix + 1) < 128u) ? fx        : 0.0f;
    // map (wx0@x0, wx1@x1) onto loaded pair (v[xe], v[xe+1])
    p.wa = (ix == -1) ? wx1 : ((ix == 127) ? 0.0f : wx0);
    p.wb = (ix == 127) ? wx0 : ((ix == -1) ? 0.0f : wx1);
    p.wy0 = ((unsigned)iy       < 128u) ? 1.0f - fy : 0.0f;
    p.wy1 = ((unsigned)(iy + 1) < 128u) ? fy        : 0.0f;
    p.wz0 = (vis && (unsigned)iz       < 128u) ? 1.0f - fz : 0.0f;
    p.wz1 = (vis && (unsigned)(iz + 1) < 128u) ? fz        : 0.0f;

    p.alive = vis && (ix >= -1) && (ix <= 127) && (iy >= -1) && (iy <= 127)
                  && (iz >= -1) && (iz <= 127);

    int xe = min(max(ix, 0), 126);
    int y0 = min(max(iy, 0), 127), y1 = min(max(iy + 1, 0), 127);
    int z0 = min(max(iz, 0), 127), z1 = min(max(iz + 1, 0), 127);
    if (!p.alive) { xe = 0; y0 = 0; y1 = 0; z0 = 0; z1 = 0; }  // dead -> line 0
    p.xe  = xe;
    p.b00 = (z0 << 14) | (y0 << 7);
    p.b01 = (z0 << 14) | (y1 << 7);
    p.b10 = (z1 << 14) | (y0 << 7);
    p.b11 = (z1 << 14) | (y1 << 7);
    return p;
}

__device__ __forceinline__ float combine_px(const Px& p,
                                            f2v a00, f2v a01, f2v a10, f2v a11)
{
    const float r00 = p.wa * a00.x + p.wb * a00.y;
    const float r01 = p.wa * a01.x + p.wb * a01.y;
    const float r10 = p.wa * a10.x + p.wb * a10.y;
    const float r11 = p.wa * a11.x + p.wb * a11.y;
    return p.wz0 * (p.wy0 * r00 + p.wy1 * r01)
         + p.wz1 * (p.wy0 * r10 + p.wy1 * r11);
}

// Tile 64(k) x 16(j); block = 4 waves; wave wv owns 4 consecutive rows
// (jt*16 + wv*4 + 0..3), lane -> k. All 16 paired gathers (4 rows x 4 corner
// pairs) are issued back-to-back and fenced from consumers by
// sched_barrier(0): ~16 outstanding loads/thread to cover L2/L3 miss latency
// (2x R5's depth). Wave-uniform ballot early-outs preserve mask/OOB skipping.
__global__ __launch_bounds__(256) void xfel_proj(
    const float* __restrict__ rotmat,   // [B,3,3]
    const float* __restrict__ vol,      // [L,L,L] as [D,H,W]
    float* __restrict__ out)            // [B,L,L]
{
    const int tid  = threadIdx.x;
    const int lane = tid & 63;
    const int wv   = tid >> 6;                    // 0..3
    const int t    = blockIdx.x;                  // 0..15: 2 khalf x 8 jtile
    const int b    = blockIdx.y;
    const int k    = ((t & 1) << 6) | lane;
    const int j0   = ((t >> 1) << 4) + (wv << 2); // rows j0..j0+3

    const int obase = (b * L + j0) * L + k;

    // circular mask
    const float stepw = 128.0f / 127.0f;
    const float ak  = (float)(k - 64) * stepw;
    const float ak2 = ak * ak;
    const float thr = 57.6f * 57.6f;              // (0.9*L/2)^2

    bool vis[4];
    bool any_vis = false;
    #pragma unroll
    for (int m = 0; m < 4; ++m) {
        const float aj = (float)(j0 + m - 64) * stepw;
        vis[m] = (aj * aj + ak2 < thr);
        any_vis |= vis[m];
    }
    if (__ballot((int)any_vis) == 0ull) {         // whole wave masked
        #pragma unroll
        for (int m = 0; m < 4; ++m)
            __builtin_nontemporal_store(0.0f, out + obase + m * L);
        return;
    }

    // rotation is block-uniform -> scalar loads
    const float* __restrict__ R = rotmat + b * 9;
    const float R00 = R[0], R01 = R[1], R02 = R[2];
    const float R10 = R[3], R11 = R[4], R12 = R[5];
    const float R20 = R[6], R21 = R[7], R22 = R[8];

    const float lk = -1.0f + (float)k * (2.0f / 127.0f);
    const float yc = -1.0f + 64.0f * (2.0f / 127.0f);   // lin[64]
    const float cx = yc * R10 + lk * R20 + 1.0f;
    const float cy = yc * R11 + lk * R21 + 1.0f;
    const float cz = yc * R12 + lk * R22 + 1.0f;

    const float lj0 = -1.0f + (float)j0 * (2.0f / 127.0f);

    Px p[4];
    bool any_alive = false;
    #pragma unroll
    for (int m = 0; m < 4; ++m) {
        p[m] = setup_px(lj0 + (float)m * (2.0f / 127.0f),
                        cx, cy, cz, R00, R01, R02, vis[m]);
        any_alive |= p[m].alive;
    }
    if (__ballot((int)any_alive) == 0ull) {       // whole wave outside volume
        #pragma unroll
        for (int m = 0; m < 4; ++m)
            __builtin_nontemporal_store(0.0f, out + obase + m * L);
        return;
    }

    // 16 paired gathers, all issued before any consumption
    f2v v[4][4];
    #pragma unroll
    for (int m = 0; m < 4; ++m) {
        v[m][0] = *(const f2v*)(vol + p[m].b00 + p[m].xe);
        v[m][1] = *(const f2v*)(vol + p[m].b01 + p[m].xe);
        v[m][2] = *(const f2v*)(vol + p[m].b10 + p[m].xe);
        v[m][3] = *(const f2v*)(vol + p[m].b11 + p[m].xe);
    }

    __builtin_amdgcn_sched_barrier(0);   // fence: keep all 16 loads in flight

    #pragma unroll
    for (int m = 0; m < 4; ++m) {
        const float res = combine_px(p[m], v[m][0], v[m][1], v[m][2], v[m][3]);
        __builtin_nontemporal_store(res, out + obase + m * L);
    }
}

extern "C" void kernel_launch(void* const* d_in, const int* in_sizes, int n_in,
                              void* d_out, int out_size, void* d_ws, size_t ws_size,
                              hipStream_t stream) {
    const float* rotmat = (const float*)d_in[0];
    const float* vol    = (const float*)d_in[1];
    float* out          = (float*)d_out;
    const int B = in_sizes[0] / 9;                // 2048
    dim3 grid(16, B);                             // 2 khalf x 8 jtile
    xfel_proj<<<grid, dim3(256), 0, stream>>>(rotmat, vol, out);
}